// Round 4
// baseline (322.351 us; speedup 1.0000x reference)
//
#include <hip/hip_runtime.h>

// Problem constants
#define IN_C   64
#define OUT_D  47          // (24-1)*2 - 2*1 + 3
#define XD     24
#define XSP    (XD*XD*XD)  // 13824
#define OSP    (OUT_D*OUT_D*OUT_D) // 103823
#define BATCH  16

// LDS: per-wave halo buffer for an 8x8x8 m-tile: 100 rows (10 z x 10 y),
// row stride RS=12 floats, row r holds x[gz=Bd-1+r/10][gy=Bh-1+r%10][gx=Bw-1..Bw+10]
// at idx 0..11 (only 0..9 ever read). 12r mod 32 covers all banks across
// 8-row groups -> conflict-free with the 2x2x2 lane layout (verified: 3k conflicts).
#define RS     12
#define NR     100
#define WBUF   (NR*RS)     // 1200 floats per wave

typedef float f4u  __attribute__((ext_vector_type(4), aligned(4)));
typedef float f4a8 __attribute__((ext_vector_type(4), aligned(8)));

// Effective weights: weff[c*64 + (pd*2+dd)*16 + (((ph*2+pw)*2+dh)*2+dw)]
// 256 threads: thread = c*4 + (pd*2+dd); each computes 16 entries.
__global__ void weff_prep(const float* __restrict__ w, float* __restrict__ weff) {
    const int tid = threadIdx.x;   // 256
    const int c = tid >> 2;
    const int q = tid & 3;         // q = pd*2+dd
    const int pd = q >> 1, dd = q & 1;
    float wv[27];
    const float* wc = w + (size_t)c * 64 * 27;   // weight[c][0][*]
    #pragma unroll
    for (int z = 0; z < 27; z++) wv[z] = wc[z];
    const int msk[2][2] = {{4, 3}, {6, 1}};
    const int md = msk[pd][dd];
    #pragma unroll
    for (int ph = 0; ph < 2; ph++)
    #pragma unroll
    for (int pw = 0; pw < 2; pw++)
    #pragma unroll
    for (int dh = 0; dh < 2; dh++)
    #pragma unroll
    for (int dw = 0; dw < 2; dw++) {
        const int mh = msk[ph][dh], mw = msk[pw][dw];
        float s = 0.f;
        for (int zd = 0; zd < 3; zd++) if ((md >> zd) & 1)
            for (int zh = 0; zh < 3; zh++) if ((mh >> zh) & 1)
                for (int zw = 0; zw < 3; zw++) if ((mw >> zw) & 1)
                    s += wv[zd * 9 + zh * 3 + zw];
        weff[c * 64 + q * 16 + (((ph * 2 + pw) * 2 + dh) * 2 + dw)] = s;
    }
}

// 864 blocks = 2 channel-halves (cg) x 16 n x 27 sp-tiles (8x8x8 m-space).
// XCD-L2 swizzle: b = (braw&7)*108 + braw>>3 (bijective, 864 = 8*108);
// decode cg = b&1 (pair-adjacent -> same XCD, temporally close), then
// n = (b>>1)/27, sp = (b>>1)%27 -> XCD x owns images {2x,2x+1} entirely.
// 256 threads = 4 waves; wave wv reduces channels [cg*32+8wv, +8) in a
// wave-PRIVATE LDS buffer (no barriers in the channel loop).
// Lane owns a 2x2x2 m-block (conflict-free b128 reads). 64 accs/thread.
// In-block tree reduction over the 4 waves, then wave 0 combines the two
// cg-halves via global_atomic_add_f32 (exactly 2 commutative contributions
// per cell -> deterministic; out is zeroed by hipMemsetAsync).
// launch_bounds(256,4): VGPR cap 128 -> 4 waves/SIMD -> 4 blocks/CU
// co-resident (LDS 4x19.5KB = 78KB), 16 waves/CU.
__global__ __launch_bounds__(256, 4) void tconv(const float* __restrict__ x,
                                                const float* __restrict__ weff,
                                                const float* __restrict__ bias,
                                                float* __restrict__ out) {
    __shared__ float xs[4864];      // 19 KB: 4x1200 staging, overlaid 2x2048 reduce
    int braw = blockIdx.x;
    int b = (braw & 7) * 108 + (braw >> 3);   // bijective XCD swizzle
    const int cg = b & 1;
    const int s2 = b >> 1;          // 0..431
    const int n  = s2 / 27;         // 0..15
    const int sp = s2 - n * 27;     // 0..26
    const int tz = sp / 9;
    const int r9 = sp - tz * 9;
    const int ty = r9 / 3;
    const int tx = r9 - ty * 3;
    const int Bd = tz * 8, Bh = ty * 8, Bw = tx * 8;

    const int tid = threadIdx.x;
    const int wv  = tid >> 6;       // 0..3
    const int L   = tid & 63;
    const int lz  = L >> 4;         // 0..3  (m-z pair)
    const int lyy = (L >> 2) & 3;   // 0..3  (m-y pair)
    const int lxx = L & 3;          // 0..3  (m-x pair)

    float* ws = xs + wv * WBUF;

    // one-time zero fill (invalid halo rows must read as 0)
    #pragma unroll
    for (int i = 0; i < 19; i++) xs[tid + 256 * i] = 0.f;
    __syncthreads();

    // ---- channel-invariant staging descriptors: 5 units/lane ----
    int gofs[5], lad[5], et[5];     // et: -1 skip, 0 full, 1 shift-left, 2 scalar
    #pragma unroll
    for (int k = 0; k < 5; k++) {
        int e = k * 64 + L;
        int u = e / 100;
        int r = e - u * 100;
        int z = r / 10;
        int y = r - z * 10;
        int gz = Bd - 1 + z, gy = Bh - 1 + y;
        bool rv = (e < 300) && ((unsigned)gz < (unsigned)XD) &&
                  ((unsigned)gy < (unsigned)XD);
        int gxs = Bw - 1 + 4 * u;
        int t;
        if (!rv) t = -1;
        else if (gxs < 0) t = 1;          // Bw=0,u=0: gx -1..2
        else if (gxs + 3 > XD - 1) t = 2; // Bw=16,u=2: gx 23..26
        else t = 0;
        et[k] = t;
        gofs[k] = (gz * XD + gy) * XD + (gxs < 0 ? 0 : gxs);
        lad[k] = r * RS + 4 * u;
    }

    const int c0 = cg * 32 + wv * 8;               // wave's first channel
    const float* xg = x + ((size_t)n * IN_C + c0) * XSP;

    // ---- prologue prefetch: first channel ----
    float4 pre[5];
    #pragma unroll
    for (int k = 0; k < 5; k++) {
        if (et[k] < 0) pre[k] = make_float4(0.f, 0.f, 0.f, 0.f);
        else if (et[k] == 2) pre[k] = make_float4(xg[gofs[k]], 0.f, 0.f, 0.f);
        else { f4u q = *(const f4u*)(xg + gofs[k]);
               pre[k] = make_float4(q.x, q.y, q.z, q.w); }
    }

    float acc[2][2][2][2][2][2];    // [mzi][myi][mxi][pd][ph][pw]
    float* af = &acc[0][0][0][0][0][0];
    #pragma unroll
    for (int i = 0; i < 64; i++) af[i] = 0.f;

    // lane-fixed row base: rows (2lz+za)*10 + (2lyy+ya), x offset 2lxx
    const int rb = (lz * 20 + lyy * 2) * RS + 2 * lxx;

    // ---- barrier-free channel loop (wave-private buffer), 8 channels ----
    #pragma unroll 1
    for (int cc = 0; cc < 8; cc++) {
        #pragma unroll
        for (int k = 0; k < 5; k++) {
            if (et[k] >= 0) {
                float4 c = pre[k];
                if (et[k] == 1) c = make_float4(0.f, c.x, c.y, c.z);
                *(float4*)&ws[lad[k]] = c;
            }
        }
        if (cc + 1 < 8) {
            const float* xc = xg + (size_t)(cc + 1) * XSP;
            #pragma unroll
            for (int k = 0; k < 5; k++) {
                if (et[k] < 0) continue;
                if (et[k] == 2) pre[k] = make_float4(xc[gofs[k]], 0.f, 0.f, 0.f);
                else { f4u q = *(const f4u*)(xc + gofs[k]);
                       pre[k] = make_float4(q.x, q.y, q.z, q.w); }
            }
        }

        const float* Wc = weff + (size_t)(c0 + cc) * 64;  // wave-uniform
        #pragma unroll
        for (int za = 0; za < 4; za++) {
            float xv[4][4];
            #pragma unroll
            for (int ya = 0; ya < 4; ya++) {
                f4a8 v = *(const f4a8*)&ws[rb + (za * 10 + ya) * RS];
                xv[ya][0] = v.x; xv[ya][1] = v.y;
                xv[ya][2] = v.z; xv[ya][3] = v.w;
            }
            // za = mzi + pd + dd
            #pragma unroll
            for (int mzi = 0; mzi < 2; mzi++)
            #pragma unroll
            for (int pd = 0; pd < 2; pd++)
            #pragma unroll
            for (int dd = 0; dd < 2; dd++) {
                if (mzi + pd + dd != za) continue;
                const float* Wg = Wc + (pd * 2 + dd) * 16;
                #pragma unroll
                for (int ph = 0; ph < 2; ph++)
                #pragma unroll
                for (int pw = 0; pw < 2; pw++)
                #pragma unroll
                for (int dh = 0; dh < 2; dh++)
                #pragma unroll
                for (int dw = 0; dw < 2; dw++) {
                    const float wgt = Wg[((ph * 2 + pw) * 2 + dh) * 2 + dw];
                    #pragma unroll
                    for (int myi = 0; myi < 2; myi++)
                    #pragma unroll
                    for (int mxi = 0; mxi < 2; mxi++)
                        acc[mzi][myi][mxi][pd][ph][pw] +=
                            wgt * xv[myi + ph + dh][mxi + pw + dw];
                }
            }
        }
    }

    // ---- in-block tree reduction over the 4 waves (2 levels) ----
    __syncthreads();
    // L1: wv1 -> xs[0..2047], wv3 -> xs[2048..4095], in halves of 32 floats
    #pragma unroll
    for (int h = 0; h < 2; h++) {
        if (wv == 1 || wv == 3) {
            float* R = xs + (wv >> 1) * 2048;
            #pragma unroll
            for (int j = 0; j < 8; j++)
                *(float4*)&R[(j * 64 + L) * 4] = *(float4*)&af[(h * 8 + j) * 4];
        }
        __syncthreads();
        if (wv == 0 || wv == 2) {
            const float* R = xs + (wv >> 1) * 2048;
            #pragma unroll
            for (int j = 0; j < 8; j++) {
                float4 v = *(const float4*)&R[(j * 64 + L) * 4];
                af[(h * 8 + j) * 4 + 0] += v.x;
                af[(h * 8 + j) * 4 + 1] += v.y;
                af[(h * 8 + j) * 4 + 2] += v.z;
                af[(h * 8 + j) * 4 + 3] += v.w;
            }
        }
        __syncthreads();
    }
    // L2: wv2 -> wv0, in halves
    #pragma unroll
    for (int h = 0; h < 2; h++) {
        if (wv == 2) {
            #pragma unroll
            for (int j = 0; j < 8; j++)
                *(float4*)&xs[(j * 64 + L) * 4] = *(float4*)&af[(h * 8 + j) * 4];
        }
        __syncthreads();
        if (wv == 0) {
            #pragma unroll
            for (int j = 0; j < 8; j++) {
                float4 v = *(const float4*)&xs[(j * 64 + L) * 4];
                af[(h * 8 + j) * 4 + 0] += v.x;
                af[(h * 8 + j) * 4 + 1] += v.y;
                af[(h * 8 + j) * 4 + 2] += v.z;
                af[(h * 8 + j) * 4 + 3] += v.w;
            }
        }
        __syncthreads();
    }

    // ---- epilogue: wave 0 combines the two cg-halves via atomics ----
    if (wv == 0) {
        const float badd = (cg == 0) ? bias[0] * 64.0f : 0.0f;
        float* on = out + (size_t)n * OSP;
        #pragma unroll
        for (int mzi = 0; mzi < 2; mzi++)
        #pragma unroll
        for (int pd = 0; pd < 2; pd++) {
            const int od = 2 * (Bd + 2 * lz + mzi) + pd;
            if (od >= OUT_D) continue;
            #pragma unroll
            for (int myi = 0; myi < 2; myi++)
            #pragma unroll
            for (int ph = 0; ph < 2; ph++) {
                const int oh = 2 * (Bh + 2 * lyy + myi) + ph;
                if (oh >= OUT_D) continue;
                const size_t rowo = ((size_t)od * OUT_D + oh) * OUT_D;
                #pragma unroll
                for (int mxi = 0; mxi < 2; mxi++)
                #pragma unroll
                for (int pw = 0; pw < 2; pw++) {
                    const int ow = 2 * (Bw + 2 * lxx + mxi) + pw;
                    if (ow < OUT_D)
                        unsafeAtomicAdd(&on[rowo + ow],
                            acc[mzi][myi][mxi][pd][ph][pw] * 64.0f + badd);
                }
            }
        }
    }
}

extern "C" void kernel_launch(void* const* d_in, const int* in_sizes, int n_in,
                              void* d_out, int out_size, void* d_ws, size_t ws_size,
                              hipStream_t stream) {
    const float* x      = (const float*)d_in[0];
    const float* weight = (const float*)d_in[1];
    const float* bias   = (const float*)d_in[2];
    float* out = (float*)d_out;
    float* weff = (float*)d_ws;        // 64*64 floats = 16 KB

    hipLaunchKernelGGL(weff_prep, dim3(1), dim3(256), 0, stream, weight, weff);

    // zero the output: each cell receives exactly 2 atomic contributions
    hipMemsetAsync(d_out, 0, (size_t)out_size, stream);

    dim3 grid(2 * 27 * BATCH, 1, 1);   // 864 blocks
    hipLaunchKernelGGL(tconv, grid, dim3(256), 0, stream, x, weff, bias, out);
}

// Round 5
// 138.180 us; speedup vs baseline: 2.3328x; 2.3328x over previous
//
#include <hip/hip_runtime.h>

// Problem constants
#define IN_C   64
#define OUT_D  47          // (24-1)*2 - 2*1 + 3
#define XD     24
#define XSP    (XD*XD*XD)  // 13824
#define OSP    (OUT_D*OUT_D*OUT_D) // 103823
#define BATCH  16

// LDS: per-wave halo buffer for a 4x8x8 m-tile: 60 rows (6 z x 10 y),
// row stride RS=12 floats, row r holds x[gz=Bd-1+r/10][gy=Bh-1+r%10][gx=Bw-1..Bw+10]
// at idx 0..11 (only 0..9 ever read). 12r mod 32 covers all 32 banks across
// 8-row groups; read pattern (4 lanes/start-bank, even spread) matches the
// measured-conflict-free R1 class (~3k conflicts).
#define RS     12
#define NR     60
#define WBUF   (NR*RS)     // 720 floats per wave

typedef float f4u  __attribute__((ext_vector_type(4), aligned(4)));
typedef float f4a8 __attribute__((ext_vector_type(4), aligned(8)));

// Effective weights: weff[c*64 + (pd*2+dd)*16 + (((ph*2+pw)*2+dh)*2+dw)]
// 256 threads: thread = c*4 + (pd*2+dd); each computes 16 entries.
__global__ void weff_prep(const float* __restrict__ w, float* __restrict__ weff) {
    const int tid = threadIdx.x;   // 256
    const int c = tid >> 2;
    const int q = tid & 3;         // q = pd*2+dd
    const int pd = q >> 1, dd = q & 1;
    float wv[27];
    const float* wc = w + (size_t)c * 64 * 27;   // weight[c][0][*]
    #pragma unroll
    for (int z = 0; z < 27; z++) wv[z] = wc[z];
    const int msk[2][2] = {{4, 3}, {6, 1}};
    const int md = msk[pd][dd];
    #pragma unroll
    for (int ph = 0; ph < 2; ph++)
    #pragma unroll
    for (int pw = 0; pw < 2; pw++)
    #pragma unroll
    for (int dh = 0; dh < 2; dh++)
    #pragma unroll
    for (int dw = 0; dw < 2; dw++) {
        const int mh = msk[ph][dh], mw = msk[pw][dw];
        float s = 0.f;
        for (int zd = 0; zd < 3; zd++) if ((md >> zd) & 1)
            for (int zh = 0; zh < 3; zh++) if ((mh >> zh) & 1)
                for (int zw = 0; zw < 3; zw++) if ((mw >> zw) & 1)
                    s += wv[zd * 9 + zh * 3 + zw];
        weff[c * 64 + q * 16 + (((ph * 2 + pw) * 2 + dh) * 2 + dw)] = s;
    }
}

// 864 blocks = 54 sp-tiles (4x8x8 m-space: 6 tz x 3 ty x 3 tx) x 16 n.
// No channel split -> each block reduces ALL 64 channels internally and
// does plain coalesced stores (no atomics, no combine pass).
// XCD-L2 swizzle: b = (braw&7)*108 + braw>>3 (bijective, 864 = 8*108);
// n = b/54, sp = b%54 -> XCD x owns images {2x,2x+1} entirely, walked
// sp-contiguously (tx fastest) -> ~3.5 MB/image stays in its XCD L2.
// 256 threads = 4 waves; wave wv reduces channels [16wv,16wv+16) in a
// wave-PRIVATE LDS buffer (no barriers in the channel loop).
// Lane owns a 1x2x2 m-block: lz=L>>4 (m-z), lyy=(L>>2)&3 (y-pair),
// lxx=L&3 (x-pair). 32 accs/thread; 12 b128 reads per 256 FMAs.
// Small footprint (16 KB LDS, ~80 VGPR) -> co-residency is grid-limited:
// 3.375 blocks/CU ~= 3.4 waves/SIMD, ~2.8x R1's effective concurrency.
__global__ __launch_bounds__(256, 4) void tconv(const float* __restrict__ x,
                                                const float* __restrict__ weff,
                                                const float* __restrict__ bias,
                                                float* __restrict__ out) {
    __shared__ float xs[4096];      // 16 KB: 4x720 staging, overlaid 2x2048 reduce
    int braw = blockIdx.x;
    int b = (braw & 7) * 108 + (braw >> 3);   // bijective XCD swizzle
    const int n  = b / 54;          // 0..15
    const int sp = b - n * 54;      // 0..53
    const int tz = sp / 9;          // 0..5
    const int r9 = sp - tz * 9;
    const int ty = r9 / 3;
    const int tx = r9 - ty * 3;
    const int Bd = tz * 4, Bh = ty * 8, Bw = tx * 8;

    const int tid = threadIdx.x;
    const int wv  = tid >> 6;       // 0..3
    const int L   = tid & 63;
    const int lz  = L >> 4;         // 0..3  (single m-z)
    const int lyy = (L >> 2) & 3;   // 0..3  (m-y pair)
    const int lxx = L & 3;          // 0..3  (m-x pair)

    float* ws = xs + wv * WBUF;

    // one-time zero fill (invalid halo rows must read as 0)
    #pragma unroll
    for (int i = 0; i < 16; i++) xs[tid + 256 * i] = 0.f;
    __syncthreads();

    // ---- channel-invariant staging descriptors: 3 units/lane ----
    // unit e = u*60 + r (u = x-quad 0..2, r = row): consecutive lanes get
    // consecutive r -> bank-spread b128 writes.
    int gofs[3], lad[3], et[3];     // et: -1 skip, 0 full, 1 shift-left, 2 scalar
    #pragma unroll
    for (int k = 0; k < 3; k++) {
        int e = k * 64 + L;
        int u = e / 60;
        int r = e - u * 60;
        int z = r / 10;
        int y = r - z * 10;
        int gz = Bd - 1 + z, gy = Bh - 1 + y;
        bool rv = (e < 180) && ((unsigned)gz < (unsigned)XD) &&
                  ((unsigned)gy < (unsigned)XD);
        int gxs = Bw - 1 + 4 * u;
        int t;
        if (!rv) t = -1;
        else if (gxs < 0) t = 1;          // Bw=0,u=0: gx -1..2
        else if (gxs + 3 > XD - 1) t = 2; // Bw=16,u=2: gx 23..26
        else t = 0;
        et[k] = t;
        gofs[k] = (gz * XD + gy) * XD + (gxs < 0 ? 0 : gxs);
        lad[k] = r * RS + 4 * u;
    }

    const float* xg = x + ((size_t)n * IN_C + wv * 16) * XSP;

    // ---- prologue prefetch: channel 0 ----
    float4 pre[3];
    #pragma unroll
    for (int k = 0; k < 3; k++) {
        if (et[k] < 0) pre[k] = make_float4(0.f, 0.f, 0.f, 0.f);
        else if (et[k] == 2) pre[k] = make_float4(xg[gofs[k]], 0.f, 0.f, 0.f);
        else { f4u q = *(const f4u*)(xg + gofs[k]);
               pre[k] = make_float4(q.x, q.y, q.z, q.w); }
    }

    float acc[2][2][2][2][2];       // [myi][mxi][pd][ph][pw]
    float* af = &acc[0][0][0][0][0];
    #pragma unroll
    for (int i = 0; i < 32; i++) af[i] = 0.f;

    // lane-fixed row base: rows (lz + za)*10 + (2lyy + ya), x offset 2lxx
    const int rb = (lz * 10 + lyy * 2) * RS + 2 * lxx;

    // ---- barrier-free channel loop (wave-private buffer), 16 channels ----
    #pragma unroll 1
    for (int cc = 0; cc < 16; cc++) {
        #pragma unroll
        for (int k = 0; k < 3; k++) {
            if (et[k] >= 0) {
                float4 c = pre[k];
                if (et[k] == 1) c = make_float4(0.f, c.x, c.y, c.z);
                *(float4*)&ws[lad[k]] = c;
            }
        }
        if (cc + 1 < 16) {
            const float* xc = xg + (size_t)(cc + 1) * XSP;
            #pragma unroll
            for (int k = 0; k < 3; k++) {
                if (et[k] < 0) continue;
                if (et[k] == 2) pre[k] = make_float4(xc[gofs[k]], 0.f, 0.f, 0.f);
                else { f4u q = *(const f4u*)(xc + gofs[k]);
                       pre[k] = make_float4(q.x, q.y, q.z, q.w); }
            }
        }

        const float* Wc = weff + (size_t)(wv * 16 + cc) * 64;  // wave-uniform
        #pragma unroll
        for (int za = 0; za < 3; za++) {
            float xv[4][4];
            #pragma unroll
            for (int ya = 0; ya < 4; ya++) {
                f4a8 v = *(const f4a8*)&ws[rb + (za * 10 + ya) * RS];
                xv[ya][0] = v.x; xv[ya][1] = v.y;
                xv[ya][2] = v.z; xv[ya][3] = v.w;
            }
            // za = pd + dd
            #pragma unroll
            for (int pd = 0; pd < 2; pd++)
            #pragma unroll
            for (int dd = 0; dd < 2; dd++) {
                if (pd + dd != za) continue;
                const float* Wg = Wc + (pd * 2 + dd) * 16;
                #pragma unroll
                for (int ph = 0; ph < 2; ph++)
                #pragma unroll
                for (int pw = 0; pw < 2; pw++)
                #pragma unroll
                for (int dh = 0; dh < 2; dh++)
                #pragma unroll
                for (int dw = 0; dw < 2; dw++) {
                    const float wgt = Wg[((ph * 2 + pw) * 2 + dh) * 2 + dw];
                    #pragma unroll
                    for (int myi = 0; myi < 2; myi++)
                    #pragma unroll
                    for (int mxi = 0; mxi < 2; mxi++)
                        acc[myi][mxi][pd][ph][pw] +=
                            wgt * xv[myi + ph + dh][mxi + pw + dw];
                }
            }
        }
    }

    // ---- in-block tree reduction over the 4 waves (2 levels, 32 fl/lane) ----
    __syncthreads();
    // L1: wv1 -> xs[0..2047], wv3 -> xs[2048..4095] (single pass)
    if (wv == 1 || wv == 3) {
        float* R = xs + (wv >> 1) * 2048;
        #pragma unroll
        for (int j = 0; j < 8; j++)
            *(float4*)&R[(j * 64 + L) * 4] = *(float4*)&af[j * 4];
    }
    __syncthreads();
    if (wv == 0 || wv == 2) {
        const float* R = xs + (wv >> 1) * 2048;
        #pragma unroll
        for (int j = 0; j < 8; j++) {
            float4 v = *(const float4*)&R[(j * 64 + L) * 4];
            af[j * 4 + 0] += v.x; af[j * 4 + 1] += v.y;
            af[j * 4 + 2] += v.z; af[j * 4 + 3] += v.w;
        }
    }
    __syncthreads();
    // L2: wv2 -> wv0
    if (wv == 2) {
        #pragma unroll
        for (int j = 0; j < 8; j++)
            *(float4*)&xs[(j * 64 + L) * 4] = *(float4*)&af[j * 4];
    }
    __syncthreads();
    if (wv == 0) {
        #pragma unroll
        for (int j = 0; j < 8; j++) {
            float4 v = *(const float4*)&xs[(j * 64 + L) * 4];
            af[j * 4 + 0] += v.x; af[j * 4 + 1] += v.y;
            af[j * 4 + 2] += v.z; af[j * 4 + 3] += v.w;
        }

        // ---- epilogue: plain stores by wave 0 ----
        const float b0 = bias[0] * 64.0f;
        float* on = out + (size_t)n * OSP;
        const int mz = Bd + lz;
        #pragma unroll
        for (int pd = 0; pd < 2; pd++) {
            const int od = 2 * mz + pd;
            if (od >= OUT_D) continue;
            #pragma unroll
            for (int myi = 0; myi < 2; myi++)
            #pragma unroll
            for (int ph = 0; ph < 2; ph++) {
                const int oh = 2 * (Bh + 2 * lyy + myi) + ph;
                if (oh >= OUT_D) continue;
                const size_t rowo = ((size_t)od * OUT_D + oh) * OUT_D;
                #pragma unroll
                for (int mxi = 0; mxi < 2; mxi++)
                #pragma unroll
                for (int pw = 0; pw < 2; pw++) {
                    const int ow = 2 * (Bw + 2 * lxx + mxi) + pw;
                    if (ow < OUT_D)
                        on[rowo + ow] =
                            acc[myi][mxi][pd][ph][pw] * 64.0f + b0;
                }
            }
        }
    }
}

extern "C" void kernel_launch(void* const* d_in, const int* in_sizes, int n_in,
                              void* d_out, int out_size, void* d_ws, size_t ws_size,
                              hipStream_t stream) {
    const float* x      = (const float*)d_in[0];
    const float* weight = (const float*)d_in[1];
    const float* bias   = (const float*)d_in[2];
    float* out = (float*)d_out;
    float* weff = (float*)d_ws;        // 64*64 floats = 16 KB

    hipLaunchKernelGGL(weff_prep, dim3(1), dim3(256), 0, stream, weight, weff);

    dim3 grid(54 * BATCH, 1, 1);       // 864 blocks
    hipLaunchKernelGGL(tconv, grid, dim3(256), 0, stream, x, weff, bias, out);
}